// Round 2
// baseline (225.462 us; speedup 1.0000x reference)
//
#include <hip/hip_runtime.h>
#include <math.h>

// Sobel gradient magnitude, zero-padded 3x3 cross stencil.
// x: [8, 64, 256, 256] f32 -> out same shape.
// gv = x[i+1,j] - x[i-1,j]; gh = x[i,j+1] - x[i,j-1]; out = sqrt(gv^2+gh^2+eps)
//
// Layout insight: W=256 = 64 lanes x float4, so ONE WAVE == ONE ROW.
// Horizontal neighbors come from __shfl (no extra loads); lane 0/63
// boundaries coincide exactly with the zero-pad boundary.
// Each wave register-blocks R=4 rows: 6 row loads -> 4 rows out.

#define PLANE_H 256
#define PLANE_W 256
#define R 4   // rows per wave

__global__ __launch_bounds__(256) void sobel_kernel(const float* __restrict__ x,
                                                    float* __restrict__ out) {
    const int tid  = threadIdx.x;
    const int lane = tid & 63;
    const int w    = blockIdx.x * 4 + (tid >> 6);    // global wave id
    const int plane = w >> 6;                        // 64 wave-groups per plane
    const int r0    = (w & 63) << 2;                 // first of 4 rows

    const size_t base = ((size_t)plane << 16) + ((size_t)r0 << 8) + ((size_t)lane << 2);
    const float* p = x + base;

    // 6-row register window: rows r0-1 .. r0+4 (zero outside plane).
    float4 win[R + 2];
    win[0] = (r0 > 0) ? *(const float4*)(p - PLANE_W) : make_float4(0.f, 0.f, 0.f, 0.f);
#pragma unroll
    for (int i = 0; i < R; ++i)
        win[i + 1] = *(const float4*)(p + (i << 8));
    win[R + 1] = (r0 + R < PLANE_H) ? *(const float4*)(p + (R << 8))
                                    : make_float4(0.f, 0.f, 0.f, 0.f);

    float* po = out + base;
    const float eps = 1e-6f;

#pragma unroll
    for (int i = 0; i < R; ++i) {
        float4 c  = win[i + 1];
        float4 up = win[i];
        float4 dn = win[i + 2];

        // horizontal halo from neighbor lanes; wave edge == plane edge -> 0
        float left  = __shfl_up(c.w, 1, 64);
        float right = __shfl_down(c.x, 1, 64);
        if (lane == 0)  left  = 0.f;
        if (lane == 63) right = 0.f;

        float gh0 = c.y   - left;
        float gh1 = c.z   - c.x;
        float gh2 = c.w   - c.y;
        float gh3 = right - c.z;

        float gv0 = dn.x - up.x;
        float gv1 = dn.y - up.y;
        float gv2 = dn.z - up.z;
        float gv3 = dn.w - up.w;

        float4 o;
        o.x = sqrtf(gv0 * gv0 + gh0 * gh0 + eps);
        o.y = sqrtf(gv1 * gv1 + gh1 * gh1 + eps);
        o.z = sqrtf(gv2 * gv2 + gh2 * gh2 + eps);
        o.w = sqrtf(gv3 * gv3 + gh3 * gh3 + eps);

        *(float4*)(po + (i << 8)) = o;
    }
}

extern "C" void kernel_launch(void* const* d_in, const int* in_sizes, int n_in,
                              void* d_out, int out_size, void* d_ws, size_t ws_size,
                              hipStream_t stream) {
    const float* x = (const float*)d_in[0];
    float* out = (float*)d_out;
    // 8*64 planes, 64 waves/plane (4 rows each), 4 waves/block
    int planes = out_size / (PLANE_H * PLANE_W);     // 512
    int totalWaves = planes * (PLANE_H / R);         // 32768
    int block = 256;
    int grid = totalWaves / 4;                       // 8192
    sobel_kernel<<<grid, block, 0, stream>>>(x, out);
}